// Round 14
// baseline (103.249 us; speedup 1.0000x reference)
//
#include <hip/hip_runtime.h>

typedef _Float16 f16x8 __attribute__((ext_vector_type(8)));
typedef _Float16 f16x4 __attribute__((ext_vector_type(4)));
typedef float    f32x4 __attribute__((ext_vector_type(4)));

// ---------------- workspace layout (bytes) ----------------
#define A16_OFF   0u
#define V16_OFF   16777216u
#define WAP_OFF   33554432u   // fragment-packed Wa fp16: 24*16*64*8*2 = 393216 B
#define WVP_OFF   33947648u
#define CORRT_OFF 34340864u
#define WBT_OFF   34471936u

#define SCHED0() __builtin_amdgcn_sched_barrier(0)
#define SBAR()   __builtin_amdgcn_s_barrier()

__device__ __forceinline__ void gl_lds16(const void* g, void* l) {
    __builtin_amdgcn_global_load_lds(
        (const __attribute__((address_space(1))) void*)g,
        (__attribute__((address_space(3))) void*)l, 16, 0, 0);
}

__device__ __forceinline__ void vwait(int n) {
    switch (n) {
        case 0: asm volatile("s_waitcnt vmcnt(0)" ::: "memory"); break;
        case 8: asm volatile("s_waitcnt vmcnt(8)" ::: "memory"); break;
        default: asm volatile("s_waitcnt vmcnt(0)" ::: "memory"); break;
    }
}

// =========================================================
// k_prep: (blocks 0..191) Wa/Wv [768,256] fp32 -> MFMA-fragment-
//  packed fp16 (kc-major). (192..215) corr->corrT, Wb->WbT.
// =========================================================
__global__ __launch_bounds__(256) void k_prep(
    const float* __restrict__ Wa, const float* __restrict__ Wv,
    const float* __restrict__ corr, const float* __restrict__ Wb,
    _Float16* __restrict__ WaP, _Float16* __restrict__ WvP,
    _Float16* __restrict__ corrT, _Float16* __restrict__ WbT)
{
    __shared__ _Float16 tile[64][72];
    int bid = blockIdx.x;
    int t = threadIdx.x;
    if (bid < 192) {
        int z = bid >= 96;
        int b = z ? bid - 96 : bid;
        const float* W = z ? Wv : Wa;
        _Float16* P = z ? WvP : WaP;
        int kc = b >> 2, nbg = b & 3;
        int l = t & 63, sub = t >> 6;
        int nb = nbg * 4 + sub;
        int q = l >> 4, lm = l & 15;
        int k0 = kc * 32 + q * 8;
        int n = nb * 16 + lm;
        _Float16 tmp[8];
        #pragma unroll
        for (int e = 0; e < 8; ++e)
            tmp[e] = (_Float16)W[(size_t)(k0 + e) * 256 + n];
        *reinterpret_cast<f16x8*>(P + ((size_t)(kc * 16 + nb) * 64 + l) * 8) =
            *reinterpret_cast<const f16x8*>(tmp);
    } else {
        int b2 = bid - 192;
        const float* src; _Float16* dst; int R, C, tr, tc;
        if (b2 < 16) { src = corr; dst = corrT; R = 256; C = 256; tr = b2 >> 2; tc = b2 & 3; }
        else         { src = Wb;   dst = WbT;   R = 512; C = 64;  tr = b2 - 16; tc = 0;      }
        int r0 = tr * 64, c0 = tc * 64;
        #pragma unroll
        for (int it = 0; it < 16; ++it) {
            int idx = t + it * 256;
            int r = idx >> 6, c = idx & 63;
            tile[r][c] = (_Float16)src[(size_t)(r0 + r) * C + (c0 + c)];
        }
        __syncthreads();
        #pragma unroll
        for (int it = 0; it < 16; ++it) {
            int idx = t + it * 256;
            int c = idx >> 6, r = idx & 63;
            dst[(size_t)(c0 + c) * R + (r0 + r)] = tile[r][c];
        }
    }
}

// =========================================================
// k_proj v14: chunk-resident B + free-running waves.
//  BM=256, 512 thr (8 waves); wave owns rows w*32..w*32+31 x all
//  256 cols (acc 2x16 frags = 128 VGPR). K = 4 chunks of 192:
//  per chunk: stage B-chunk (96 KB fragment-packed, gl_lds) ONCE,
//  barrier; then 3 substeps (BK=64) with NO barriers: per-wave
//  plain f32x4 A loads in frag layout (ping-pong reg sets,
//  counted vmcnt(8)), cvt fp16, 64 MFMA vs LDS-resident B.
//  Only 2 barriers/chunk -> waves slip; memory sees a continuous
//  stream (copy regime) instead of the per-step burst-drain that
//  capped v4-v13 at ~2.3 TB/s.
//  LDS 96 KB (1 block/CU). 256 blocks, XCD-chunked swizzle.
// =========================================================
__global__ __launch_bounds__(512, 1) void k_proj(
    const float* __restrict__ Xa, const float* __restrict__ Xv,
    const _Float16* __restrict__ WaP, const _Float16* __restrict__ WvP,
    const float* __restrict__ ba, const float* __restrict__ bv,
    _Float16* __restrict__ Aout, _Float16* __restrict__ Vout)
{
    extern __shared__ __align__(16) char smem[];   // 98304 B: B chunk (and epilogue)

    const int bid = blockIdx.x;
    const int lin = (bid & 7) * 32 + (bid >> 3);   // bijective XCD swizzle, 0..255
    const int z = lin >> 7, mb = lin & 127;
    const float*    X    = z ? Xv  : Xa;
    const _Float16* WP   = z ? WvP : WaP;
    const float*    bias = z ? bv  : ba;
    _Float16*       Out  = z ? Vout : Aout;
    const int m0 = mb * 256;

    const int t = threadIdx.x, lane = t & 63, w = t >> 6;
    const int q = lane >> 4, lm = lane & 15;

    const float* Xw = X + (size_t)(m0 + w * 32) * 768;   // wave's 32 rows

    f32x4 acc[2][16] = {};
    f32x4 ra[8], rb[8];

    // plain loads of one 32-row x 64-k fp32 sub-tile in frag layout
    auto loadA = [&](int k0, f32x4* s) {
        #pragma unroll
        for (int mf = 0; mf < 2; ++mf)
            #pragma unroll
            for (int kk = 0; kk < 2; ++kk)
                #pragma unroll
                for (int h = 0; h < 2; ++h)
                    s[mf * 4 + kk * 2 + h] = *reinterpret_cast<const f32x4*>(
                        Xw + (size_t)(mf * 16 + lm) * 768 + k0 + kk * 32 + q * 8 + h * 4);
    };
    // stage one 96-KB fragment-packed B chunk (kc = 6c..6c+5)
    auto stageB = [&](int c) {
        #pragma unroll
        for (int it = 0; it < 12; ++it) {
            int u0 = it * 512 + w * 64;          // wave-uniform chunk base
            gl_lds16(WP + ((size_t)c * 6144 + u0 + lane) * 8, smem + u0 * 16);
        }
    };

    #pragma unroll
    for (int c = 0; c < 4; ++c) {
        const int k0 = c * 192;
        SBAR();                                  // Bs free (prev chunk consumed)
        stageB(c);                               // 12 DMA / thread
        loadA(k0, ra);                           // 8 plain loads (substep 0)
        vwait(8); SCHED0();                      // forces the 12 B DMAs; A0 stays in flight
        SBAR();                                  // B chunk visible to all waves

        #pragma unroll
        for (int s = 0; s < 3; ++s) {
            f32x4* cur = (s & 1) ? rb : ra;
            f32x4* nxt = (s & 1) ? ra : rb;
            if (s < 2) loadA(k0 + (s + 1) * 64, nxt);   // issue next substep
            vwait(s < 2 ? 8 : 0); SCHED0();             // force cur landed, keep nxt flying
            // cvt cur -> fp16 fragments
            f16x8 af[2][2];
            #pragma unroll
            for (int mf = 0; mf < 2; ++mf)
                #pragma unroll
                for (int kk = 0; kk < 2; ++kk) {
                    f16x4 l4 = __builtin_convertvector(cur[mf * 4 + kk * 2], f16x4);
                    f16x4 h4 = __builtin_convertvector(cur[mf * 4 + kk * 2 + 1], f16x4);
                    af[mf][kk] = __builtin_shufflevector(l4, h4, 0, 1, 2, 3, 4, 5, 6, 7);
                }
            // 64 MFMA vs LDS-resident B (compiler inserts lgkmcnt)
            #pragma unroll
            for (int kk = 0; kk < 2; ++kk) {
                const int kcl = s * 2 + kk;
                #pragma unroll
                for (int nf = 0; nf < 16; ++nf) {
                    f16x8 bf = *reinterpret_cast<const f16x8*>(
                        smem + (((kcl * 16 + nf) * 64) + lane) * 16);
                    acc[0][nf] = __builtin_amdgcn_mfma_f32_16x16x32_f16(af[0][kk], bf, acc[0][nf], 0, 0, 0);
                    acc[1][nf] = __builtin_amdgcn_mfma_f32_16x16x32_f16(af[1][kk], bf, acc[1][nf], 0, 0, 0);
                }
            }
        }
    }

    // ---- epilogue: acc (+bias) -> LDS fp16 [128][256] halves -> coalesced ----
    float biasv[16];
    #pragma unroll
    for (int nf = 0; nf < 16; ++nf)
        biasv[nf] = bias[nf * 16 + lm];

    _Float16* Cs = (_Float16*)smem;              // 64 KB of the 96 KB
    #pragma unroll
    for (int h = 0; h < 2; ++h) {
        __syncthreads();
        if ((w >> 2) == h) {
            int rbase = (w & 3) * 32;
            #pragma unroll
            for (int mf = 0; mf < 2; ++mf)
                #pragma unroll
                for (int nf = 0; nf < 16; ++nf)
                    #pragma unroll
                    for (int r = 0; r < 4; ++r)
                        Cs[(rbase + mf * 16 + q * 4 + r) * 256 + nf * 16 + lm] =
                            (_Float16)(acc[mf][nf][r] + biasv[nf]);
        }
        __syncthreads();
        #pragma unroll
        for (int it = 0; it < 8; ++it) {
            int idx = t + it * 512;
            int row = idx >> 5, c8 = idx & 31;
            f16x8 vv = *reinterpret_cast<const f16x8*>(Cs + row * 256 + c8 * 8);
            *reinterpret_cast<f16x8*>(Out + (size_t)(m0 + h * 128 + row) * 256 + c8 * 8) = vv;
        }
    }
}

// =========================================================
// k_fuse: per-batch (512 blocks, 256 thr = 4 waves) — unchanged
// =========================================================
#define SM_A    0u
#define SM_V    33792u
#define SM_AC   67584u
#define SM_CC   101376u
#define SM_ATA  118272u
#define SM_ATV  127488u
#define SM_AWT  136704u
#define SM_VWT  145920u
#define SM_RED  155136u
#define SM_TOTAL 159232u

__global__ __launch_bounds__(256) void k_fuse(
    const _Float16* __restrict__ A16, const _Float16* __restrict__ V16,
    const _Float16* __restrict__ corrT, const _Float16* __restrict__ WbT,
    const float* __restrict__ bb, const float* __restrict__ gamma,
    const float* __restrict__ beta, float* __restrict__ out)
{
    extern __shared__ char sm[];
    _Float16* a_s   = (_Float16*)(sm + SM_A);
    _Float16* v_s   = (_Float16*)(sm + SM_V);
    _Float16* ac_s  = (_Float16*)(sm + SM_AC);
    float*    cc_s  = (float*)(sm + SM_CC);
    _Float16* attAT = (_Float16*)(sm + SM_ATA);
    _Float16* attV  = (_Float16*)(sm + SM_ATV);
    _Float16* awT   = (_Float16*)(sm + SM_AWT);
    _Float16* vwT   = (_Float16*)(sm + SM_VWT);
    float*    red   = (float*)(sm + SM_RED);

    const int b = blockIdx.x;
    const int t = threadIdx.x, lane = t & 63, w = t >> 6;
    const int q = lane >> 4, lm = lane & 15;

    const _Float16* Ab = A16 + (size_t)b * 64 * 256;
    const _Float16* Vb = V16 + (size_t)b * 64 * 256;
    #pragma unroll
    for (int it = 0; it < 8; ++it) {
        int idx = t + it * 256;
        int row = idx >> 5, kc = idx & 31;
        *reinterpret_cast<f16x8*>(a_s + row * 264 + kc * 8) =
            *reinterpret_cast<const f16x8*>(Ab + row * 256 + kc * 8);
        *reinterpret_cast<f16x8*>(v_s + row * 264 + kc * 8) =
            *reinterpret_cast<const f16x8*>(Vb + row * 256 + kc * 8);
    }
    __syncthreads();

    // ac = a @ corr
    {
        f32x4 acc[4][4] = {};
        for (int ks = 0; ks < 8; ++ks) {
            f16x8 af[4];
            #pragma unroll
            for (int mf = 0; mf < 4; ++mf)
                af[mf] = *reinterpret_cast<const f16x8*>(a_s + (mf * 16 + lm) * 264 + ks * 32 + q * 8);
            #pragma unroll
            for (int nf = 0; nf < 4; ++nf) {
                int e = w * 64 + nf * 16 + lm;
                f16x8 bf = *reinterpret_cast<const f16x8*>(corrT + (size_t)e * 256 + ks * 32 + q * 8);
                #pragma unroll
                for (int mf = 0; mf < 4; ++mf)
                    acc[mf][nf] = __builtin_amdgcn_mfma_f32_16x16x32_f16(af[mf], bf, acc[mf][nf], 0, 0, 0);
            }
        }
        #pragma unroll
        for (int mf = 0; mf < 4; ++mf)
            #pragma unroll
            for (int nf = 0; nf < 4; ++nf)
                #pragma unroll
                for (int r = 0; r < 4; ++r)
                    ac_s[(mf * 16 + 4 * q + r) * 264 + (w * 64 + nf * 16 + lm)] = (_Float16)acc[mf][nf][r];
    }
    __syncthreads();

    // cc = ac @ v^T
    {
        f32x4 acc[4] = {};
        for (int ks = 0; ks < 8; ++ks) {
            f16x8 bf = *reinterpret_cast<const f16x8*>(v_s + (w * 16 + lm) * 264 + ks * 32 + q * 8);
            #pragma unroll
            for (int mf = 0; mf < 4; ++mf) {
                f16x8 af = *reinterpret_cast<const f16x8*>(ac_s + (mf * 16 + lm) * 264 + ks * 32 + q * 8);
                acc[mf] = __builtin_amdgcn_mfma_f32_16x16x32_f16(af, bf, acc[mf], 0, 0, 0);
            }
        }
        #pragma unroll
        for (int mf = 0; mf < 4; ++mf)
            #pragma unroll
            for (int r = 0; r < 4; ++r)
                cc_s[(mf * 16 + 4 * q + r) * 66 + (w * 16 + lm)] = acc[mf][r];
    }
    __syncthreads();

    // dual softmax (+identity)
    {
        int j = t & 63, seg = w;
        float cmx = -1e30f, rmx = -1e30f;
        #pragma unroll
        for (int k = 0; k < 16; ++k) {
            int i = seg * 16 + k;
            cmx = fmaxf(cmx, cc_s[i * 66 + j]);
            rmx = fmaxf(rmx, cc_s[j * 66 + i]);
        }
        red[0 * 256 + seg * 64 + j] = cmx;
        red[2 * 256 + seg * 64 + j] = rmx;
        __syncthreads();
        float cm = fmaxf(fmaxf(red[0 * 256 + 0 * 64 + j], red[0 * 256 + 1 * 64 + j]),
                         fmaxf(red[0 * 256 + 2 * 64 + j], red[0 * 256 + 3 * 64 + j]));
        float rm = fmaxf(fmaxf(red[2 * 256 + 0 * 64 + j], red[2 * 256 + 1 * 64 + j]),
                         fmaxf(red[2 * 256 + 2 * 64 + j], red[2 * 256 + 3 * 64 + j]));
        float cs = 0.f, rs = 0.f;
        #pragma unroll
        for (int k = 0; k < 16; ++k) {
            int i = seg * 16 + k;
            cs += __expf(cc_s[i * 66 + j] - cm);
            rs += __expf(cc_s[j * 66 + i] - rm);
        }
        red[1 * 256 + seg * 64 + j] = cs;
        red[3 * 256 + seg * 64 + j] = rs;
        __syncthreads();
        float csum = red[1 * 256 + 0 * 64 + j] + red[1 * 256 + 1 * 64 + j] +
                     red[1 * 256 + 2 * 64 + j] + red[1 * 256 + 3 * 64 + j];
        float rsum = red[3 * 256 + 0 * 64 + j] + red[3 * 256 + 1 * 64 + j] +
                     red[3 * 256 + 2 * 64 + j] + red[3 * 256 + 3 * 64 + j];
        float cinv = 1.f / csum, rinv = 1.f / rsum;
        #pragma unroll
        for (int k = 0; k < 16; ++k) {
            int i = seg * 16 + k;
            float pa = __expf(cc_s[i * 66 + j] - cm) * cinv;
            if (i == j) pa += 1.f;
            attAT[j * 72 + i] = (_Float16)pa;
            float pv = __expf(cc_s[j * 66 + i] - rm) * rinv;
            if (i == j) pv += 1.f;
            attV[j * 72 + i] = (_Float16)pv;
        }
    }

    // aw = a@Wb_top (waves 0,1), vw = v@Wb_bot (waves 2,3)
    {
        int isV = w >> 1, wcol = w & 1;
        const _Float16* src = isV ? v_s : a_s;
        const int doff = isV ? 256 : 0;
        f32x4 acc[4][2] = {};
        for (int ks = 0; ks < 8; ++ks) {
            f16x8 af[4];
            #pragma unroll
            for (int mf = 0; mf < 4; ++mf)
                af[mf] = *reinterpret_cast<const f16x8*>(src + (mf * 16 + lm) * 264 + ks * 32 + q * 8);
            #pragma unroll
            for (int nf = 0; nf < 2; ++nf) {
                int o = wcol * 32 + nf * 16 + lm;
                f16x8 bf = *reinterpret_cast<const f16x8*>(WbT + (size_t)o * 512 + doff + ks * 32 + q * 8);
                #pragma unroll
                for (int mf = 0; mf < 4; ++mf)
                    acc[mf][nf] = __builtin_amdgcn_mfma_f32_16x16x32_f16(af[mf], bf, acc[mf][nf], 0, 0, 0);
            }
        }
        _Float16* dst = isV ? vwT : awT;
        #pragma unroll
        for (int mf = 0; mf < 4; ++mf)
            #pragma unroll
            for (int nf = 0; nf < 2; ++nf)
                #pragma unroll
                for (int r = 0; r < 4; ++r)
                    dst[(wcol * 32 + nf * 16 + lm) * 72 + (mf * 16 + 4 * q + r)] = (_Float16)acc[mf][nf][r];
    }
    __syncthreads();

    // h = attA^T@aw + attV@vw
    f32x4 hacc[4] = {};
    #pragma unroll
    for (int kk = 0; kk < 2; ++kk) {
        f16x8 a1 = *reinterpret_cast<const f16x8*>(attAT + (16 * w + lm) * 72 + kk * 32 + q * 8);
        f16x8 a2 = *reinterpret_cast<const f16x8*>(attV  + (16 * w + lm) * 72 + kk * 32 + q * 8);
        #pragma unroll
        for (int nf = 0; nf < 4; ++nf) {
            f16x8 b1 = *reinterpret_cast<const f16x8*>(awT + (nf * 16 + lm) * 72 + kk * 32 + q * 8);
            f16x8 b2 = *reinterpret_cast<const f16x8*>(vwT + (nf * 16 + lm) * 72 + kk * 32 + q * 8);
            hacc[nf] = __builtin_amdgcn_mfma_f32_16x16x32_f16(a1, b1, hacc[nf], 0, 0, 0);
            hacc[nf] = __builtin_amdgcn_mfma_f32_16x16x32_f16(a2, b2, hacc[nf], 0, 0, 0);
        }
    }

    // +bb, LayerNorm, ReLU, store
    {
        float bbv[4], gv[4], bev[4];
        #pragma unroll
        for (int nf = 0; nf < 4; ++nf) {
            int o = nf * 16 + lm;
            bbv[nf] = bb[o]; gv[nf] = gamma[o]; bev[nf] = beta[o];
        }
        #pragma unroll
        for (int r = 0; r < 4; ++r) {
            float vals[4]; float s1 = 0.f, s2 = 0.f;
            #pragma unroll
            for (int nf = 0; nf < 4; ++nf) {
                float hv = hacc[nf][r] + bbv[nf];
                vals[nf] = hv; s1 += hv; s2 += hv * hv;
            }
            #pragma unroll
            for (int m = 1; m < 16; m <<= 1) {
                s1 += __shfl_xor(s1, m, 64);
                s2 += __shfl_xor(s2, m, 64);
            }
            float mu = s1 * 0.015625f;
            float var = s2 * 0.015625f - mu * mu;
            float rstd = rsqrtf(var + 1e-5f);
            int s = 16 * w + 4 * q + r;
            float* orow = out + ((size_t)b * 64 + s) * 64;
            #pragma unroll
            for (int nf = 0; nf < 4; ++nf) {
                float y = (vals[nf] - mu) * rstd * gv[nf] + bev[nf];
                orow[nf * 16 + lm] = fmaxf(y, 0.f);
            }
        }
    }
}

// =========================================================
extern "C" void kernel_launch(void* const* d_in, const int* in_sizes, int n_in,
                              void* d_out, int out_size, void* d_ws, size_t ws_size,
                              hipStream_t stream) {
    const float* Xa    = (const float*)d_in[0];
    const float* Xv    = (const float*)d_in[1];
    const float* Wa    = (const float*)d_in[2];
    const float* ba    = (const float*)d_in[3];
    const float* Wv    = (const float*)d_in[4];
    const float* bv    = (const float*)d_in[5];
    const float* corr  = (const float*)d_in[6];
    const float* Wb    = (const float*)d_in[7];
    const float* bb    = (const float*)d_in[8];
    const float* gamma = (const float*)d_in[9];
    const float* beta  = (const float*)d_in[10];
    float* out = (float*)d_out;
    char* ws = (char*)d_ws;

    _Float16* a16   = (_Float16*)(ws + A16_OFF);
    _Float16* v16   = (_Float16*)(ws + V16_OFF);
    _Float16* WaP   = (_Float16*)(ws + WAP_OFF);
    _Float16* WvP   = (_Float16*)(ws + WVP_OFF);
    _Float16* corrT = (_Float16*)(ws + CORRT_OFF);
    _Float16* WbT   = (_Float16*)(ws + WBT_OFF);

    hipLaunchKernelGGL(k_prep, dim3(216), dim3(256), 0, stream,
                       Wa, Wv, corr, Wb, WaP, WvP, corrT, WbT);
    (void)hipFuncSetAttribute((const void*)k_proj,
                              hipFuncAttributeMaxDynamicSharedMemorySize, 98304);
    hipLaunchKernelGGL(k_proj, dim3(256), dim3(512), 98304, stream,
                       Xa, Xv, WaP, WvP, ba, bv, a16, v16);
    (void)hipFuncSetAttribute((const void*)k_fuse,
                              hipFuncAttributeMaxDynamicSharedMemorySize, SM_TOTAL);
    hipLaunchKernelGGL(k_fuse, dim3(512), dim3(256), SM_TOTAL, stream,
                       a16, v16, corrT, WbT, bb, gamma, beta, out);
}

// Round 15
// 86.771 us; speedup vs baseline: 1.1899x; 1.1899x over previous
//
#include <hip/hip_runtime.h>

typedef _Float16 f16x8 __attribute__((ext_vector_type(8)));
typedef _Float16 f16x4 __attribute__((ext_vector_type(4)));
typedef float    f32x4 __attribute__((ext_vector_type(4)));

// ---------------- workspace layout (bytes) ----------------
#define A16_OFF   0u
#define V16_OFF   16777216u
#define WAP_OFF   33554432u   // fragment-packed Wa fp16: 24*16*64*8*2 = 393216 B
#define WVP_OFF   33947648u
#define CORRT_OFF 34340864u
#define WBT_OFF   34471936u

#define SCHED0() __builtin_amdgcn_sched_barrier(0)
#define SBAR()   __builtin_amdgcn_s_barrier()

__device__ __forceinline__ void gl_lds16(const void* g, void* l) {
    __builtin_amdgcn_global_load_lds(
        (const __attribute__((address_space(1))) void*)g,
        (__attribute__((address_space(3))) void*)l, 16, 0, 0);
}

// =========================================================
// k_prep: (blocks 0..191) Wa/Wv [768,256] fp32 -> MFMA-fragment-
//  packed fp16: fragment (kc,nb) = 64 lanes x 16B contiguous, lane
//  l=(q,lm) holds W[kc*32+q*8+e][nb*16+lm].
//  (blocks 192..215) transpose+cvt corr -> corrT, Wb -> WbT.
// =========================================================
__global__ __launch_bounds__(256) void k_prep(
    const float* __restrict__ Wa, const float* __restrict__ Wv,
    const float* __restrict__ corr, const float* __restrict__ Wb,
    _Float16* __restrict__ WaP, _Float16* __restrict__ WvP,
    _Float16* __restrict__ corrT, _Float16* __restrict__ WbT)
{
    __shared__ _Float16 tile[64][72];
    int bid = blockIdx.x;
    int t = threadIdx.x;
    if (bid < 192) {
        int z = bid >= 96;
        int b = z ? bid - 96 : bid;
        const float* W = z ? Wv : Wa;
        _Float16* P = z ? WvP : WaP;
        int kc = b >> 2, nbg = b & 3;
        int l = t & 63, sub = t >> 6;
        int nb = nbg * 4 + sub;
        int q = l >> 4, lm = l & 15;
        int k0 = kc * 32 + q * 8;
        int n = nb * 16 + lm;
        _Float16 tmp[8];
        #pragma unroll
        for (int e = 0; e < 8; ++e)
            tmp[e] = (_Float16)W[(size_t)(k0 + e) * 256 + n];
        *reinterpret_cast<f16x8*>(P + ((size_t)(kc * 16 + nb) * 64 + l) * 8) =
            *reinterpret_cast<const f16x8*>(tmp);
    } else {
        int b2 = bid - 192;
        const float* src; _Float16* dst; int R, C, tr, tc;
        if (b2 < 16) { src = corr; dst = corrT; R = 256; C = 256; tr = b2 >> 2; tc = b2 & 3; }
        else         { src = Wb;   dst = WbT;   R = 512; C = 64;  tr = b2 - 16; tc = 0;      }
        int r0 = tr * 64, c0 = tc * 64;
        #pragma unroll
        for (int it = 0; it < 16; ++it) {
            int idx = t + it * 256;
            int r = idx >> 6, c = idx & 63;
            tile[r][c] = (_Float16)src[(size_t)(r0 + r) * C + (c0 + c)];
        }
        __syncthreads();
        #pragma unroll
        for (int it = 0; it < 16; ++it) {
            int idx = t + it * 256;
            int c = idx >> 6, r = idx & 63;
            dst[(size_t)(c0 + c) * R + (r0 + r)] = tile[r][c];
        }
    }
}

// =========================================================
// k_proj v11 (best measured: 85.9 us total, R11): BM=256 amortizes
//  the B re-stream; counted-vmcnt double-buffered global_load_lds
//  pipeline. BM=256, BN=256, BK=32; 512 thr (8 waves, 4Mx2N; wave
//  64x128). LDS (dynamic 96 KB): A fp32 dbuf 2x32K (xor-swizzle via
//  source), B fp16 dbuf 2x16K (fragment-packed linear). 256 blocks
//  (1/CU). Per step: [A frags + B frags + 32 MFMA] lgkm0 SBAR
//  [stage ks+2: 6 DMA/wave] vmcnt(6) SBAR.
// =========================================================
__global__ __launch_bounds__(512, 1) void k_proj(
    const float* __restrict__ Xa, const float* __restrict__ Xv,
    const _Float16* __restrict__ WaP, const _Float16* __restrict__ WvP,
    const float* __restrict__ ba, const float* __restrict__ bv,
    _Float16* __restrict__ Aout, _Float16* __restrict__ Vout)
{
    extern __shared__ __align__(16) char smem[];  // [0,64K): A dbuf  [64K,96K): B dbuf

    // bijective XCD-chunked swizzle for 256 blocks (8 x 32)
    const int bid = blockIdx.x;
    const int lin = (bid & 7) * 32 + (bid >> 3);   // 0..255
    const int z = lin >> 7, mb = lin & 127;
    const float*    X    = z ? Xv  : Xa;
    const _Float16* WP   = z ? WvP : WaP;
    const float*    bias = z ? bv  : ba;
    _Float16*       Out  = z ? Vout : Aout;
    const int m0 = mb * 256;

    const int t = threadIdx.x, lane = t & 63, w = t >> 6;
    const int wr = w >> 1, wc = w & 1;          // wave tile: rows 64*wr, cols 128*wc
    const int q = lane >> 4, lm = lane & 15;

    f32x4 acc[4][8] = {};

    auto stageA = [&](int ks, int buf) {
        char* base = smem + buf * 32768;
        #pragma unroll
        for (int it = 0; it < 4; ++it) {
            int idx0 = it * 512 + w * 64;       // wave-uniform chunk base
            int idx = idx0 + lane;              // 0..2047: r=idx>>3, c=idx&7
            int r = idx >> 3, c = idx & 7;
            int gc = c ^ (r & 7);               // inverse swizzle on global source
            gl_lds16(X + (size_t)(m0 + r) * 768 + ks * 32 + gc * 4,
                     base + idx0 * 16);
        }
    };
    auto stageB = [&](int ks, int buf) {
        char* base = smem + 65536 + buf * 16384;
        #pragma unroll
        for (int it = 0; it < 2; ++it) {
            int idx0 = it * 512 + w * 64;
            gl_lds16(WP + ((size_t)ks * 1024 + idx0 + lane) * 8,
                     base + idx0 * 16);
        }
    };

    // prologue: two tiles in flight; confirm tile 0 only (vmcnt(6))
    stageA(0, 0); stageB(0, 0);
    stageA(1, 1); stageB(1, 1);
    asm volatile("s_waitcnt vmcnt(6)" ::: "memory"); SCHED0();
    SBAR();

    for (int ks = 0; ks < 24; ++ks) {
        const int cur = ks & 1;
        const char* Ac = smem + cur * 32768;
        const char* Bc = smem + 65536 + cur * 16384;

        // ---- A fragments (fp32 in LDS -> fp16 regs) ----
        f16x8 af[4];
        #pragma unroll
        for (int mf = 0; mf < 4; ++mf) {
            int r = wr * 64 + mf * 16 + lm;
            const char* base = Ac + r * 128;
            int c0 = (2 * q) ^ (r & 7);
            int c1 = (2 * q + 1) ^ (r & 7);
            f32x4 lo = *reinterpret_cast<const f32x4*>(base + c0 * 16);
            f32x4 hi = *reinterpret_cast<const f32x4*>(base + c1 * 16);
            f16x4 l4 = __builtin_convertvector(lo, f16x4);
            f16x4 h4 = __builtin_convertvector(hi, f16x4);
            af[mf] = __builtin_shufflevector(l4, h4, 0, 1, 2, 3, 4, 5, 6, 7);
        }
        // ---- B frag + MFMA interleaved ----
        #pragma unroll
        for (int nf = 0; nf < 8; ++nf) {
            int nb = wc * 8 + nf;
            f16x8 bf = *reinterpret_cast<const f16x8*>(Bc + (nb * 64 + lane) * 16);
            #pragma unroll
            for (int mf = 0; mf < 4; ++mf)
                acc[mf][nf] = __builtin_amdgcn_mfma_f32_16x16x32_f16(af[mf], bf, acc[mf][nf], 0, 0, 0);
        }
        asm volatile("s_waitcnt lgkmcnt(0)" ::: "memory"); SCHED0();
        SBAR();                                  // all waves done reading buf[cur]
        // ---- refill freed buffer (lands ~1.8 steps later) ----
        if (ks + 2 < 24) { stageA(ks + 2, cur); stageB(ks + 2, cur); }
        // ---- counted wait: tile ks+1 ready, tile ks+2 stays in flight ----
        if (ks < 22)      { asm volatile("s_waitcnt vmcnt(6)" ::: "memory"); }
        else if (ks == 22){ asm volatile("s_waitcnt vmcnt(0)" ::: "memory"); }
        SCHED0();
        if (ks < 23) SBAR();
    }

    // ---- epilogue: two 128-row halves through 64 KB of LDS ----
    float biasv[8];
    #pragma unroll
    for (int nf = 0; nf < 8; ++nf)
        biasv[nf] = bias[wc * 128 + nf * 16 + lm];

    _Float16* Cs = (_Float16*)smem;   // 64 KB = 128 x 256 fp16
    #pragma unroll
    for (int h = 0; h < 2; ++h) {
        __syncthreads();
        if ((wr >> 1) == h) {
            int rbase = (wr & 1) * 64;           // local row within half
            #pragma unroll
            for (int mf = 0; mf < 4; ++mf)
                #pragma unroll
                for (int nf = 0; nf < 8; ++nf)
                    #pragma unroll
                    for (int r = 0; r < 4; ++r)
                        Cs[(rbase + mf * 16 + q * 4 + r) * 256 + wc * 128 + nf * 16 + lm] =
                            (_Float16)(acc[mf][nf][r] + biasv[nf]);
        }
        __syncthreads();
        #pragma unroll
        for (int it = 0; it < 8; ++it) {
            int idx = t + it * 512;
            int row = idx >> 5, c = idx & 31;
            f16x8 vv = *reinterpret_cast<const f16x8*>(Cs + row * 256 + c * 8);
            *reinterpret_cast<f16x8*>(Out + (size_t)(m0 + h * 128 + row) * 256 + c * 8) = vv;
        }
    }
}

// =========================================================
// k_fuse: per-batch (512 blocks, 256 thr = 4 waves) — unchanged
// =========================================================
#define SM_A    0u
#define SM_V    33792u
#define SM_AC   67584u
#define SM_CC   101376u
#define SM_ATA  118272u
#define SM_ATV  127488u
#define SM_AWT  136704u
#define SM_VWT  145920u
#define SM_RED  155136u
#define SM_TOTAL 159232u

__global__ __launch_bounds__(256) void k_fuse(
    const _Float16* __restrict__ A16, const _Float16* __restrict__ V16,
    const _Float16* __restrict__ corrT, const _Float16* __restrict__ WbT,
    const float* __restrict__ bb, const float* __restrict__ gamma,
    const float* __restrict__ beta, float* __restrict__ out)
{
    extern __shared__ char sm[];
    _Float16* a_s   = (_Float16*)(sm + SM_A);
    _Float16* v_s   = (_Float16*)(sm + SM_V);
    _Float16* ac_s  = (_Float16*)(sm + SM_AC);
    float*    cc_s  = (float*)(sm + SM_CC);
    _Float16* attAT = (_Float16*)(sm + SM_ATA);
    _Float16* attV  = (_Float16*)(sm + SM_ATV);
    _Float16* awT   = (_Float16*)(sm + SM_AWT);
    _Float16* vwT   = (_Float16*)(sm + SM_VWT);
    float*    red   = (float*)(sm + SM_RED);

    const int b = blockIdx.x;
    const int t = threadIdx.x, lane = t & 63, w = t >> 6;
    const int q = lane >> 4, lm = lane & 15;

    const _Float16* Ab = A16 + (size_t)b * 64 * 256;
    const _Float16* Vb = V16 + (size_t)b * 64 * 256;
    #pragma unroll
    for (int it = 0; it < 8; ++it) {
        int idx = t + it * 256;
        int row = idx >> 5, kc = idx & 31;
        *reinterpret_cast<f16x8*>(a_s + row * 264 + kc * 8) =
            *reinterpret_cast<const f16x8*>(Ab + row * 256 + kc * 8);
        *reinterpret_cast<f16x8*>(v_s + row * 264 + kc * 8) =
            *reinterpret_cast<const f16x8*>(Vb + row * 256 + kc * 8);
    }
    __syncthreads();

    // ac = a @ corr
    {
        f32x4 acc[4][4] = {};
        for (int ks = 0; ks < 8; ++ks) {
            f16x8 af[4];
            #pragma unroll
            for (int mf = 0; mf < 4; ++mf)
                af[mf] = *reinterpret_cast<const f16x8*>(a_s + (mf * 16 + lm) * 264 + ks * 32 + q * 8);
            #pragma unroll
            for (int nf = 0; nf < 4; ++nf) {
                int e = w * 64 + nf * 16 + lm;
                f16x8 bf = *reinterpret_cast<const f16x8*>(corrT + (size_t)e * 256 + ks * 32 + q * 8);
                #pragma unroll
                for (int mf = 0; mf < 4; ++mf)
                    acc[mf][nf] = __builtin_amdgcn_mfma_f32_16x16x32_f16(af[mf], bf, acc[mf][nf], 0, 0, 0);
            }
        }
        #pragma unroll
        for (int mf = 0; mf < 4; ++mf)
            #pragma unroll
            for (int nf = 0; nf < 4; ++nf)
                #pragma unroll
                for (int r = 0; r < 4; ++r)
                    ac_s[(mf * 16 + 4 * q + r) * 264 + (w * 64 + nf * 16 + lm)] = (_Float16)acc[mf][nf][r];
    }
    __syncthreads();

    // cc = ac @ v^T
    {
        f32x4 acc[4] = {};
        for (int ks = 0; ks < 8; ++ks) {
            f16x8 bf = *reinterpret_cast<const f16x8*>(v_s + (w * 16 + lm) * 264 + ks * 32 + q * 8);
            #pragma unroll
            for (int mf = 0; mf < 4; ++mf) {
                f16x8 af = *reinterpret_cast<const f16x8*>(ac_s + (mf * 16 + lm) * 264 + ks * 32 + q * 8);
                acc[mf] = __builtin_amdgcn_mfma_f32_16x16x32_f16(af, bf, acc[mf], 0, 0, 0);
            }
        }
        #pragma unroll
        for (int mf = 0; mf < 4; ++mf)
            #pragma unroll
            for (int r = 0; r < 4; ++r)
                cc_s[(mf * 16 + 4 * q + r) * 66 + (w * 16 + lm)] = acc[mf][r];
    }
    __syncthreads();

    // dual softmax (+identity)
    {
        int j = t & 63, seg = w;
        float cmx = -1e30f, rmx = -1e30f;
        #pragma unroll
        for (int k = 0; k < 16; ++k) {
            int i = seg * 16 + k;
            cmx = fmaxf(cmx, cc_s[i * 66 + j]);
            rmx = fmaxf(rmx, cc_s[j * 66 + i]);
        }
        red[0 * 256 + seg * 64 + j] = cmx;
        red[2 * 256 + seg * 64 + j] = rmx;
        __syncthreads();
        float cm = fmaxf(fmaxf(red[0 * 256 + 0 * 64 + j], red[0 * 256 + 1 * 64 + j]),
                         fmaxf(red[0 * 256 + 2 * 64 + j], red[0 * 256 + 3 * 64 + j]));
        float rm = fmaxf(fmaxf(red[2 * 256 + 0 * 64 + j], red[2 * 256 + 1 * 64 + j]),
                         fmaxf(red[2 * 256 + 2 * 64 + j], red[2 * 256 + 3 * 64 + j]));
        float cs = 0.f, rs = 0.f;
        #pragma unroll
        for (int k = 0; k < 16; ++k) {
            int i = seg * 16 + k;
            cs += __expf(cc_s[i * 66 + j] - cm);
            rs += __expf(cc_s[j * 66 + i] - rm);
        }
        red[1 * 256 + seg * 64 + j] = cs;
        red[3 * 256 + seg * 64 + j] = rs;
        __syncthreads();
        float csum = red[1 * 256 + 0 * 64 + j] + red[1 * 256 + 1 * 64 + j] +
                     red[1 * 256 + 2 * 64 + j] + red[1 * 256 + 3 * 64 + j];
        float rsum = red[3 * 256 + 0 * 64 + j] + red[3 * 256 + 1 * 64 + j] +
                     red[3 * 256 + 2 * 64 + j] + red[3 * 256 + 3 * 64 + j];
        float cinv = 1.f / csum, rinv = 1.f / rsum;
        #pragma unroll
        for (int k = 0; k < 16; ++k) {
            int i = seg * 16 + k;
            float pa = __expf(cc_s[i * 66 + j] - cm) * cinv;
            if (i == j) pa += 1.f;
            attAT[j * 72 + i] = (_Float16)pa;
            float pv = __expf(cc_s[j * 66 + i] - rm) * rinv;
            if (i == j) pv += 1.f;
            attV[j * 72 + i] = (_Float16)pv;
        }
    }

    // aw = a@Wb_top (waves 0,1), vw = v@Wb_bot (waves 2,3)
    {
        int isV = w >> 1, wcol = w & 1;
        const _Float16* src = isV ? v_s : a_s;
        const int doff = isV ? 256 : 0;
        f32x4 acc[4][2] = {};
        for (int ks = 0; ks < 8; ++ks) {
            f16x8 af[4];
            #pragma unroll
            for (int mf = 0; mf < 4; ++mf)
                af[mf] = *reinterpret_cast<const f16x8*>(src + (mf * 16 + lm) * 264 + ks * 32 + q * 8);
            #pragma unroll
            for (int nf = 0; nf < 2; ++nf) {
                int o = wcol * 32 + nf * 16 + lm;
                f16x8 bf = *reinterpret_cast<const f16x8*>(WbT + (size_t)o * 512 + doff + ks * 32 + q * 8);
                #pragma unroll
                for (int mf = 0; mf < 4; ++mf)
                    acc[mf][nf] = __builtin_amdgcn_mfma_f32_16x16x32_f16(af[mf], bf, acc[mf][nf], 0, 0, 0);
            }
        }
        _Float16* dst = isV ? vwT : awT;
        #pragma unroll
        for (int mf = 0; mf < 4; ++mf)
            #pragma unroll
            for (int nf = 0; nf < 2; ++nf)
                #pragma unroll
                for (int r = 0; r < 4; ++r)
                    dst[(wcol * 32 + nf * 16 + lm) * 72 + (mf * 16 + 4 * q + r)] = (_Float16)acc[mf][nf][r];
    }
    __syncthreads();

    // h = attA^T@aw + attV@vw
    f32x4 hacc[4] = {};
    #pragma unroll
    for (int kk = 0; kk < 2; ++kk) {
        f16x8 a1 = *reinterpret_cast<const f16x8*>(attAT + (16 * w + lm) * 72 + kk * 32 + q * 8);
        f16x8 a2 = *reinterpret_cast<const f16x8*>(attV  + (16 * w + lm) * 72 + kk * 32 + q * 8);
        #pragma unroll
        for (int nf = 0; nf < 4; ++nf) {
            f16x8 b1 = *reinterpret_cast<const f16x8*>(awT + (nf * 16 + lm) * 72 + kk * 32 + q * 8);
            f16x8 b2 = *reinterpret_cast<const f16x8*>(vwT + (nf * 16 + lm) * 72 + kk * 32 + q * 8);
            hacc[nf] = __builtin_amdgcn_mfma_f32_16x16x32_f16(a1, b1, hacc[nf], 0, 0, 0);
            hacc[nf] = __builtin_amdgcn_mfma_f32_16x16x32_f16(a2, b2, hacc[nf], 0, 0, 0);
        }
    }

    // +bb, LayerNorm, ReLU, store
    {
        float bbv[4], gv[4], bev[4];
        #pragma unroll
        for (int nf = 0; nf < 4; ++nf) {
            int o = nf * 16 + lm;
            bbv[nf] = bb[o]; gv[nf] = gamma[o]; bev[nf] = beta[o];
        }
        #pragma unroll
        for (int r = 0; r < 4; ++r) {
            float vals[4]; float s1 = 0.f, s2 = 0.f;
            #pragma unroll
            for (int nf = 0; nf < 4; ++nf) {
                float hv = hacc[nf][r] + bbv[nf];
                vals[nf] = hv; s1 += hv; s2 += hv * hv;
            }
            #pragma unroll
            for (int m = 1; m < 16; m <<= 1) {
                s1 += __shfl_xor(s1, m, 64);
                s2 += __shfl_xor(s2, m, 64);
            }
            float mu = s1 * 0.015625f;
            float var = s2 * 0.015625f - mu * mu;
            float rstd = rsqrtf(var + 1e-5f);
            int s = 16 * w + 4 * q + r;
            float* orow = out + ((size_t)b * 64 + s) * 64;
            #pragma unroll
            for (int nf = 0; nf < 4; ++nf) {
                float y = (vals[nf] - mu) * rstd * gv[nf] + bev[nf];
                orow[nf * 16 + lm] = fmaxf(y, 0.f);
            }
        }
    }
}

// =========================================================
extern "C" void kernel_launch(void* const* d_in, const int* in_sizes, int n_in,
                              void* d_out, int out_size, void* d_ws, size_t ws_size,
                              hipStream_t stream) {
    const float* Xa    = (const float*)d_in[0];
    const float* Xv    = (const float*)d_in[1];
    const float* Wa    = (const float*)d_in[2];
    const float* ba    = (const float*)d_in[3];
    const float* Wv    = (const float*)d_in[4];
    const float* bv    = (const float*)d_in[5];
    const float* corr  = (const float*)d_in[6];
    const float* Wb    = (const float*)d_in[7];
    const float* bb    = (const float*)d_in[8];
    const float* gamma = (const float*)d_in[9];
    const float* beta  = (const float*)d_in[10];
    float* out = (float*)d_out;
    char* ws = (char*)d_ws;

    _Float16* a16   = (_Float16*)(ws + A16_OFF);
    _Float16* v16   = (_Float16*)(ws + V16_OFF);
    _Float16* WaP   = (_Float16*)(ws + WAP_OFF);
    _Float16* WvP   = (_Float16*)(ws + WVP_OFF);
    _Float16* corrT = (_Float16*)(ws + CORRT_OFF);
    _Float16* WbT   = (_Float16*)(ws + WBT_OFF);

    hipLaunchKernelGGL(k_prep, dim3(216), dim3(256), 0, stream,
                       Wa, Wv, corr, Wb, WaP, WvP, corrT, WbT);
    (void)hipFuncSetAttribute((const void*)k_proj,
                              hipFuncAttributeMaxDynamicSharedMemorySize, 98304);
    hipLaunchKernelGGL(k_proj, dim3(256), dim3(512), 98304, stream,
                       Xa, Xv, WaP, WvP, ba, bv, a16, v16);
    (void)hipFuncSetAttribute((const void*)k_fuse,
                              hipFuncAttributeMaxDynamicSharedMemorySize, SM_TOTAL);
    hipLaunchKernelGGL(k_fuse, dim3(512), dim3(256), SM_TOTAL, stream,
                       a16, v16, corrT, WbT, bb, gamma, beta, out);
}